// Round 20
// baseline (170.323 us; speedup 1.0000x reference)
//
#include <hip/hip_runtime.h>
#include <hip/hip_bf16.h>

typedef unsigned short u16;
typedef unsigned int u32;
typedef __attribute__((ext_vector_type(8))) __bf16 bf16x8;
typedef __attribute__((ext_vector_type(4))) float f32x4;
typedef __attribute__((ext_vector_type(16))) float f32x16;

#define LOG2E 1.4426950408889634f

__device__ __forceinline__ u16 f2bf(float f) {
  union { __hip_bfloat16 h; u16 u; } cv;
  cv.h = __float2bfloat16(f);
  return cv.u;
}

__device__ __forceinline__ float bf2f(u16 u) {
  union { u32 u; float f; } cv;
  cv.u = ((u32)u) << 16;
  return cv.f;
}

__device__ __forceinline__ u32 pk2(float a, float b) {
  return (u32)f2bf(a) | ((u32)f2bf(b) << 16);
}

// raw v_exp_f32 (2^x, ~1 ULP) — avoids OCML range-reduction sequence
#define EXP2 __builtin_amdgcn_exp2f

__device__ __forceinline__ f32x4 mfma16(bf16x8 a, bf16x8 b, f32x4 c) {
  return __builtin_amdgcn_mfma_f32_16x16x32_bf16(a, b, c, 0, 0, 0);
}
__device__ __forceinline__ f32x16 mfma32(bf16x8 a, bf16x8 b, f32x16 c) {
  return __builtin_amdgcn_mfma_f32_32x32x16_bf16(a, b, c, 0, 0, 0);
}

// async global->LDS, 16B per lane, dest = wave-uniform base + lane*16
__device__ __forceinline__ void gload16(const u16* g, u16* lds) {
  __builtin_amdgcn_global_load_lds(
      (const __attribute__((address_space(1))) u32*)g,
      (__attribute__((address_space(3))) u32*)lds, 16, 0, 0);
}

// merge two bf16x8 partials and normalize: bit-identical to old merge kernel
__device__ __forceinline__ bf16x8 merge8(bf16x8 a, bf16x8 b, float li) {
  union { bf16x8 v; u16 e[8]; } ua, ub, uo;
  ua.v = a; ub.v = b;
#pragma unroll
  for (int i = 0; i < 8; i++)
    uo.e[i] = f2bf((bf2f(ua.e[i]) + bf2f(ub.e[i])) * li);
  return uo.v;
}

// ---- fused prep: 4x weight cast+transpose (LDS-tiled) + ln1 (one launch) ----
// blocks [0,768): casts; [768, 2816): ln1 rows (4 rows/block, 1 wave each).
__global__ __launch_bounds__(256) void prep_kernel(
    const float* __restrict__ w_qkv, u16* __restrict__ wqkvT,
    const float* __restrict__ w_proj, u16* __restrict__ wprojT,
    const float* __restrict__ w1, u16* __restrict__ w1T,
    const float* __restrict__ w2, u16* __restrict__ w2T,
    const float* __restrict__ X, const float* __restrict__ gam,
    const float* __restrict__ bet, u16* __restrict__ Y) {
  __shared__ float T[64][65];
  const int bid = blockIdx.x;
  if (bid < 768) {
    const float* W; u16* WT; int K, N, base;
    if (bid < 192)      { W = w_qkv; WT = wqkvT; K = 512;  N = 1536; base = 0; }
    else if (bid < 256) { W = w_proj; WT = wprojT; K = 512; N = 512; base = 192; }
    else if (bid < 512) { W = w1;   WT = w1T;   K = 512;  N = 2048; base = 256; }
    else                { W = w2;   WT = w2T;   K = 2048; N = 512;  base = 512; }
    int b = bid - base;
    int ntx = N >> 6;
    int bx = b % ntx, by = b / ntx;
    int tx = threadIdx.x & 63, ty = threadIdx.x >> 6;
#pragma unroll
    for (int i = 0; i < 64; i += 4)
      T[ty + i][tx] = W[(size_t)(by * 64 + ty + i) * N + bx * 64 + tx];
    __syncthreads();
#pragma unroll
    for (int i = 0; i < 64; i += 4)
      WT[(size_t)(bx * 64 + ty + i) * K + by * 64 + tx] = f2bf(T[tx][ty + i]);
  } else {
    int wid = threadIdx.x >> 6, l = threadIdx.x & 63;
    int row = (bid - 768) * 4 + wid;
    const float4* xp = reinterpret_cast<const float4*>(X + (size_t)row * 512);
    float4 a = xp[l], c = xp[l + 64];
    float s  = a.x + a.y + a.z + a.w + c.x + c.y + c.z + c.w;
    float s2 = a.x*a.x + a.y*a.y + a.z*a.z + a.w*a.w
             + c.x*c.x + c.y*c.y + c.z*c.z + c.w*c.w;
#pragma unroll
    for (int m = 1; m < 64; m <<= 1) { s += __shfl_xor(s, m); s2 += __shfl_xor(s2, m); }
    float mu = s * (1.f / 512.f);
    float rs = rsqrtf(s2 * (1.f / 512.f) - mu * mu + 1e-5f);
    const float4* gp = reinterpret_cast<const float4*>(gam);
    const float4* bp = reinterpret_cast<const float4*>(bet);
    float4 g0 = gp[l], g1 = gp[l + 64], b0 = bp[l], b1 = bp[l + 64];
    ushort4 o;
    o.x = f2bf((a.x - mu) * rs * g0.x + b0.x);
    o.y = f2bf((a.y - mu) * rs * g0.y + b0.y);
    o.z = f2bf((a.z - mu) * rs * g0.z + b0.z);
    o.w = f2bf((a.w - mu) * rs * g0.w + b0.w);
    reinterpret_cast<ushort4*>(Y + (size_t)row * 512)[l] = o;
    o.x = f2bf((c.x - mu) * rs * g1.x + b1.x);
    o.y = f2bf((c.y - mu) * rs * g1.y + b1.y);
    o.z = f2bf((c.z - mu) * rs * g1.z + b1.z);
    o.w = f2bf((c.w - mu) * rs * g1.w + b1.w);
    reinterpret_cast<ushort4*>(Y + (size_t)row * 512)[l + 64] = o;
  }
}

// ---- LayerNorm over 512, 4 waves/block (1 row per wave), f32 -> bf16 ----
__global__ __launch_bounds__(256) void ln4_kernel(const float* __restrict__ X,
                                                  const float* __restrict__ gam,
                                                  const float* __restrict__ bet,
                                                  u16* __restrict__ Y) {
  int wid = threadIdx.x >> 6, l = threadIdx.x & 63;
  int row = blockIdx.x * 4 + wid;
  const float4* xp = reinterpret_cast<const float4*>(X + (size_t)row * 512);
  float4 a = xp[l], c = xp[l + 64];
  float s  = a.x + a.y + a.z + a.w + c.x + c.y + c.z + c.w;
  float s2 = a.x*a.x + a.y*a.y + a.z*a.z + a.w*a.w
           + c.x*c.x + c.y*c.y + c.z*c.z + c.w*c.w;
#pragma unroll
  for (int m = 1; m < 64; m <<= 1) { s += __shfl_xor(s, m); s2 += __shfl_xor(s2, m); }
  float mu = s * (1.f / 512.f);
  float rs = rsqrtf(s2 * (1.f / 512.f) - mu * mu + 1e-5f);
  const float4* gp = reinterpret_cast<const float4*>(gam);
  const float4* bp = reinterpret_cast<const float4*>(bet);
  float4 g0 = gp[l], g1 = gp[l + 64], b0 = bp[l], b1 = bp[l + 64];
  ushort4 o;
  o.x = f2bf((a.x - mu) * rs * g0.x + b0.x);
  o.y = f2bf((a.y - mu) * rs * g0.y + b0.y);
  o.z = f2bf((a.z - mu) * rs * g0.z + b0.z);
  o.w = f2bf((a.w - mu) * rs * g0.w + b0.w);
  reinterpret_cast<ushort4*>(Y + (size_t)row * 512)[l] = o;
  o.x = f2bf((c.x - mu) * rs * g1.x + b1.x);
  o.y = f2bf((c.y - mu) * rs * g1.y + b1.y);
  o.z = f2bf((c.z - mu) * rs * g1.z + b1.z);
  o.w = f2bf((c.w - mu) * rs * g1.w + b1.w);
  reinterpret_cast<ushort4*>(Y + (size_t)row * 512)[l + 64] = o;
}

// ---- NT GEMM (BM=128, BK=64, 8 waves): qkv scatter & mlp1 gelu ----
// 8 granules/row, phys p = row*8 + (c ^ (row&7)); kk=1 read = off ^ 32 u16;
// +16-row fragment = +1024 u16 (imm-folded). 2-phase dbuf; XCD swizzle.
// EPI: 0=qkv scatter (V via ushort4)  2=gelu->bf16
template <int EPI>
__global__ __launch_bounds__(512)
__attribute__((amdgpu_waves_per_eu(4)))
void gemm_bt(const u16* __restrict__ A, const u16* __restrict__ BT,
             int M, int N, int K,
             const float* __restrict__ bias,
             u16* __restrict__ outU,
             u16* __restrict__ Qo, u16* __restrict__ Ko, u16* __restrict__ VTo) {
  constexpr int BM = 128, BN = 128, WC = 4, FM = 4;
  __shared__ u16 As[2][BM * 64];
  __shared__ u16 Bs[2][BN * 64];
  const int tid = threadIdx.x;
  const int wid = tid >> 6, l = tid & 63;
  const int lg = l >> 4, ll = l & 15;
  const int nx = gridDim.x;
  const int id = blockIdx.y * nx + blockIdx.x;
  const int cpx = (nx * gridDim.y) >> 3;
  const int wg = (id & 7) * cpx + (id >> 3);
  const int m0 = (wg / nx) * BM, n0 = (wg % nx) * BN;
  const int wm = (wid / WC) * (BM / 2), wn = (wid % WC) * 32;
  const f32x4 zf = {0.f, 0.f, 0.f, 0.f};
  f32x4 acc[FM][2];
#pragma unroll
  for (int i = 0; i < FM; i++) { acc[i][0] = zf; acc[i][1] = zf; }

  // staging: 1024 granules per matrix per buffer; 512 thr -> 2 each
  int srow[2], scol[2];
#pragma unroll
  for (int j = 0; j < 2; j++) {
    int p = j * 512 + tid;
    srow[j] = p >> 3;
    scol[j] = (p & 7) ^ (srow[j] & 7);
  }

  const int r0a = wm + ll;
  const int aoff0 = r0a * 64 + (lg ^ (r0a & 7)) * 8;
  const int r0b = wn + ll;
  const int boff0 = r0b * 64 + (lg ^ (r0b & 7)) * 8;

  auto stage = [&](int kt, int buf) {
#pragma unroll
    for (int j = 0; j < 2; j++) {
      int p = j * 512 + tid;
      gload16(A + (size_t)(m0 + srow[j]) * K + kt + scol[j] * 8, &As[buf][p * 8]);
      gload16(BT + (size_t)(n0 + srow[j]) * K + kt + scol[j] * 8, &Bs[buf][p * 8]);
    }
  };

  const int nt = K >> 6;
  stage(0, 0);
  for (int t = 0; t < nt; t++) {
    __syncthreads();
    if (t + 1 < nt) stage((t + 1) << 6, (t + 1) & 1);
    const u16* A_ = As[t & 1];
    const u16* B_ = Bs[t & 1];
#pragma unroll
    for (int kk = 0; kk < 2; kk++) {
      const int ax = kk ? (aoff0 ^ 32) : aoff0;
      const int bx = kk ? (boff0 ^ 32) : boff0;
      bf16x8 af[FM], bfr[2];
#pragma unroll
      for (int i = 0; i < FM; i++)
        af[i] = *reinterpret_cast<const bf16x8*>(A_ + ax + 1024 * i);
      bfr[0] = *reinterpret_cast<const bf16x8*>(B_ + bx);
      bfr[1] = *reinterpret_cast<const bf16x8*>(B_ + bx + 1024);
#pragma unroll
      for (int i = 0; i < FM; i++) {
        acc[i][0] = mfma16(af[i], bfr[0], acc[i][0]);
        acc[i][1] = mfma16(af[i], bfr[1], acc[i][1]);
      }
    }
  }

#pragma unroll
  for (int i = 0; i < FM; i++) {
#pragma unroll
    for (int j = 0; j < 2; j++) {
      int col = n0 + wn + j * 16 + ll;
      float bcol2 = bias[col];
      int rbase = m0 + wm + i * 16 + lg * 4;
      if (EPI == 0) {
        int bi = rbase >> 11, nseq0 = rbase & 2047;  // 4 rows stay in one b
        int t = col >> 9, rem = col & 511;
        int hh = rem >> 6, dd = rem & 63;
        if (t == 2) {
          // V transpose-scatter: 4 consecutive nseq -> one ushort4
          ushort4 v;
          v.x = f2bf(acc[i][j][0] + bcol2);
          v.y = f2bf(acc[i][j][1] + bcol2);
          v.z = f2bf(acc[i][j][2] + bcol2);
          v.w = f2bf(acc[i][j][3] + bcol2);
          *reinterpret_cast<ushort4*>(
              VTo + ((size_t)((bi << 3) + hh) * 64 + dd) * 2048 + nseq0) = v;
        } else {
          size_t hidx = ((size_t)((bi << 3) + hh) * 2048 + nseq0) * 64 + dd;
#pragma unroll
          for (int r = 0; r < 4; r++) {
            float val = acc[i][j][r] + bcol2;
            if (t == 0) Qo[hidx + (size_t)r * 64] = f2bf(val * (0.125f * LOG2E));
            else        Ko[hidx + (size_t)r * 64] = f2bf(val);
          }
        }
      } else {
#pragma unroll
        for (int r = 0; r < 4; r++) {
          float val = acc[i][j][r] + bcol2;
          // tanh-form GELU (|err| < 3e-3, overflow-safe via 1 - 2/(e+1))
          float y = 0.7978845608f * (val + 0.044715f * val * val * val);
          float e = EXP2(2.0f * LOG2E * y);
          float t2 = 1.0f - 2.0f / (e + 1.0f);
          outU[(size_t)(rbase + r) * 2048 + col] = f2bf(0.5f * val * (1.0f + t2));
        }
      }
    }
  }
}

// ---- proj GEMM with FUSED attn merge (BM=BN=BK=64, K=512 baked) ----
// A[row][k] = f2bf((O0+O1) * 1/L[row][k>>6]); K-step t == head t (BK=64
// aligns with head boundary), so linv is statically indexed by the fully
// unrolled t loop. Both partials staged to LDS; merge at fragment read.
__global__ __launch_bounds__(256)
__attribute__((amdgpu_waves_per_eu(4)))
void proj_fused(const u16* __restrict__ Opart, const float* __restrict__ Stat,
                const u16* __restrict__ BT,
                const float* __restrict__ bias,
                const float* __restrict__ resid,
                float* __restrict__ outF) {
  __shared__ u16 As0[2][64 * 64];
  __shared__ u16 As1[2][64 * 64];
  __shared__ u16 Bs[2][64 * 64];
  const int tid = threadIdx.x;
  const int wid = tid >> 6, l = tid & 63;
  const int lg = l >> 4, ll = l & 15;
  const int nx = gridDim.x;
  const int id = blockIdx.y * nx + blockIdx.x;
  const int cpx = (nx * gridDim.y) >> 3;
  const int wg = (id & 7) * cpx + (id >> 3);
  const int m0 = (wg / nx) * 64, n0 = (wg % nx) * 64;
  const int wm = (wid >> 1) * 32, wn = (wid & 1) * 32;
  const f32x4 zf = {0.f, 0.f, 0.f, 0.f};
  f32x4 acc[2][2];
  acc[0][0] = zf; acc[0][1] = zf; acc[1][0] = zf; acc[1][1] = zf;

  int srow[2], scol[2];
#pragma unroll
  for (int j = 0; j < 2; j++) {
    int p = j * 256 + tid;
    srow[j] = p >> 3;
    scol[j] = (p & 7) ^ (srow[j] & 7);
  }

  const int ra = wm + ll;
  const int aoff0 = ra * 64 + (lg ^ (ra & 7)) * 8;
  const int rb = wn + ll;
  const int boff0 = rb * 64 + (lg ^ (rb & 7)) * 8;

  // per-lane 1/L for A rows (ra, ra+16), all 8 heads (rows share b: 64-tile)
  const int row0 = m0 + ra;
  const int bb8 = (row0 >> 11) * 8;
  const int n0r = row0 & 2047;
  float linv0[8], linv1[8];
#pragma unroll
  for (int hh = 0; hh < 8; hh++) {
    size_t s0 = (size_t)(bb8 + hh) * 2048 + n0r;
    linv0[hh] = 1.0f / (Stat[s0] + Stat[65536 + s0]);
    linv1[hh] = 1.0f / (Stat[s0 + 16] + Stat[65536 + s0 + 16]);
  }

  auto stage = [&](int kt, int buf) {
#pragma unroll
    for (int j = 0; j < 2; j++) {
      int p = j * 256 + tid;
      size_t aidx = (size_t)(m0 + srow[j]) * 512 + kt + scol[j] * 8;
      gload16(Opart + aidx, &As0[buf][p * 8]);
      gload16(Opart + (size_t)8192 * 512 + aidx, &As1[buf][p * 8]);
      gload16(BT + (size_t)(n0 + srow[j]) * 512 + kt + scol[j] * 8, &Bs[buf][p * 8]);
    }
  };

  stage(0, 0);
#pragma unroll
  for (int t = 0; t < 8; t++) {
    __syncthreads();
    if (t + 1 < 8) stage((t + 1) << 6, (t + 1) & 1);
    const u16* A0_ = As0[t & 1];
    const u16* A1_ = As1[t & 1];
    const u16* B_ = Bs[t & 1];
#pragma unroll
    for (int kk = 0; kk < 2; kk++) {
      const int ax = kk ? (aoff0 ^ 32) : aoff0;
      const int bx = kk ? (boff0 ^ 32) : boff0;
      bf16x8 a0 = merge8(*reinterpret_cast<const bf16x8*>(A0_ + ax),
                         *reinterpret_cast<const bf16x8*>(A1_ + ax), linv0[t]);
      bf16x8 a1 = merge8(*reinterpret_cast<const bf16x8*>(A0_ + ax + 1024),
                         *reinterpret_cast<const bf16x8*>(A1_ + ax + 1024), linv1[t]);
      bf16x8 b0 = *reinterpret_cast<const bf16x8*>(B_ + bx);
      bf16x8 b1 = *reinterpret_cast<const bf16x8*>(B_ + bx + 1024);
      acc[0][0] = mfma16(a0, b0, acc[0][0]);
      acc[0][1] = mfma16(a0, b1, acc[0][1]);
      acc[1][0] = mfma16(a1, b0, acc[1][0]);
      acc[1][1] = mfma16(a1, b1, acc[1][1]);
    }
  }

#pragma unroll
  for (int i = 0; i < 2; i++) {
#pragma unroll
    for (int j = 0; j < 2; j++) {
      int col = n0 + wn + j * 16 + ll;
      float bcol2 = bias[col];
      int rbase = m0 + wm + i * 16 + lg * 4;
#pragma unroll
      for (int r = 0; r < 4; r++) {
        size_t idx = (size_t)(rbase + r) * 512 + col;
        outF[idx] = acc[i][j][r] + bcol2 + resid[idx];
      }
    }
  }
}

// ---- NT GEMM (BM=BN=64, BK=64, 4 waves): mlp2 (out = acc+bias+resid) ----
__global__ __launch_bounds__(256)
__attribute__((amdgpu_waves_per_eu(4)))
void gemm_bt64(const u16* __restrict__ A, const u16* __restrict__ BT,
               int M, int N, int K,
               const float* __restrict__ bias,
               const float* __restrict__ resid,
               float* __restrict__ outF) {
  __shared__ u16 As[2][64 * 64];
  __shared__ u16 Bs[2][64 * 64];
  const int tid = threadIdx.x;
  const int wid = tid >> 6, l = tid & 63;
  const int lg = l >> 4, ll = l & 15;
  const int nx = gridDim.x;
  const int id = blockIdx.y * nx + blockIdx.x;
  const int cpx = (nx * gridDim.y) >> 3;
  const int wg = (id & 7) * cpx + (id >> 3);
  const int m0 = (wg / nx) * 64, n0 = (wg % nx) * 64;
  const int wm = (wid >> 1) * 32, wn = (wid & 1) * 32;
  const f32x4 zf = {0.f, 0.f, 0.f, 0.f};
  f32x4 acc[2][2];
  acc[0][0] = zf; acc[0][1] = zf; acc[1][0] = zf; acc[1][1] = zf;

  int srow[2], scol[2];
#pragma unroll
  for (int j = 0; j < 2; j++) {
    int p = j * 256 + tid;
    srow[j] = p >> 3;
    scol[j] = (p & 7) ^ (srow[j] & 7);
  }

  const int ra = wm + ll;
  const int aoff0 = ra * 64 + (lg ^ (ra & 7)) * 8;
  const int rb = wn + ll;
  const int boff0 = rb * 64 + (lg ^ (rb & 7)) * 8;

  auto stage = [&](int kt, int buf) {
#pragma unroll
    for (int j = 0; j < 2; j++) {
      int p = j * 256 + tid;
      gload16(A + (size_t)(m0 + srow[j]) * K + kt + scol[j] * 8, &As[buf][p * 8]);
      gload16(BT + (size_t)(n0 + srow[j]) * K + kt + scol[j] * 8, &Bs[buf][p * 8]);
    }
  };

  const int nt = K >> 6;
  stage(0, 0);
  for (int t = 0; t < nt; t++) {
    __syncthreads();
    if (t + 1 < nt) stage((t + 1) << 6, (t + 1) & 1);
    const u16* A_ = As[t & 1];
    const u16* B_ = Bs[t & 1];
#pragma unroll
    for (int kk = 0; kk < 2; kk++) {
      const int ax = kk ? (aoff0 ^ 32) : aoff0;
      const int bx = kk ? (boff0 ^ 32) : boff0;
      bf16x8 a0 = *reinterpret_cast<const bf16x8*>(A_ + ax);
      bf16x8 a1 = *reinterpret_cast<const bf16x8*>(A_ + ax + 1024);
      bf16x8 b0 = *reinterpret_cast<const bf16x8*>(B_ + bx);
      bf16x8 b1 = *reinterpret_cast<const bf16x8*>(B_ + bx + 1024);
      acc[0][0] = mfma16(a0, b0, acc[0][0]);
      acc[0][1] = mfma16(a0, b1, acc[0][1]);
      acc[1][0] = mfma16(a1, b0, acc[1][0]);
      acc[1][1] = mfma16(a1, b1, acc[1][1]);
    }
  }

#pragma unroll
  for (int i = 0; i < 2; i++) {
#pragma unroll
    for (int j = 0; j < 2; j++) {
      int col = n0 + wn + j * 16 + ll;
      float bcol2 = bias[col];
      int rbase = m0 + wm + i * 16 + lg * 4;
#pragma unroll
      for (int r = 0; r < 4; r++) {
        size_t idx = (size_t)(rbase + r) * 512 + col;
        outF[idx] = acc[i][j][r] + bcol2 + resid[idx];
      }
    }
  }
}

// ---- flash attention: LDS-staged K/V, swapped-QK^T, fixed-base softmax,
// kvsplit=2, sequential subtiles, koff folded, waves_per_eu(4).
// Q[B,H,N,D] (pre-scaled by 0.125*log2e), K[B,H,N,D], VT[B,H,D,N], all bf16.
// grid (32, 8, 4): x = qtile*2 + split; 4 waves; wave owns 32 q rows; KVBLK=64.
__global__ __launch_bounds__(256)
__attribute__((amdgpu_waves_per_eu(4)))
void attn_kernel(const u16* __restrict__ Q,
                 const u16* __restrict__ Kt,
                 const u16* __restrict__ VT,
                 u16* __restrict__ Opart,
                 float* __restrict__ Stat) {
  __shared__ __align__(16) u16 Kbuf[2][64 * 64];
  __shared__ __align__(16) u16 Vbuf[2][64 * 64];
  const int tid = threadIdx.x;
  const int wid = tid >> 6, l = tid & 63;
  const int lq = l & 31, h = l >> 5;
  const int b = blockIdx.z, hd = blockIdx.y;
  const int qt = blockIdx.x >> 1, sp = blockIdx.x & 1;
  const int qbase = qt * 128 + wid * 32;
  const int kv0 = sp * 1024;
  const size_t hoff = (size_t)(b * 8 + hd) * 2048 * 64;
  const u16* Qh = Q + hoff;
  const u16* Kh = Kt + hoff;
  const u16* Vh = VT + hoff;   // [D=64][N=2048]

  bf16x8 qf[4];
#pragma unroll
  for (int s = 0; s < 4; s++)
    qf[s] = *reinterpret_cast<const bf16x8*>(Qh + (size_t)(qbase + lq) * 64 + s * 16 + h * 8);

  int koff[4];
#pragma unroll
  for (int s = 0; s < 4; s++)
    koff[s] = (lq * 8 + ((s * 2 + h) ^ (lq & 7))) * 8;

  f32x16 oacc[2];
#pragma unroll
  for (int r = 0; r < 16; r++) { oacc[0][r] = 0.f; oacc[1][r] = 0.f; }
  float ps0 = 0.f, ps1 = 0.f;

  auto stage = [&](int kb, int buf) {
#pragma unroll
    for (int half = 0; half < 2; half++) {
      int g0 = half * 256 + wid * 64;        // wave-uniform base granule
      int p = g0 + l;
      int row = p >> 3;
      int c = (p & 7) ^ (row & 7);           // logical col16 stored at phys p
      gload16(Kh + (size_t)(kb + row) * 64 + c * 8, &Kbuf[buf][g0 * 8]);
      gload16(Vh + (size_t)row * 2048 + kb + c * 8, &Vbuf[buf][g0 * 8]);
    }
  };

  stage(kv0, 0);
  for (int i = 0; i < 16; i++) {
    __syncthreads();                          // drains vmcnt -> buf[i&1] ready
    if (i < 15) stage(kv0 + (i + 1) * 64, (i + 1) & 1);
    const u16* Kc = Kbuf[i & 1];
    const u16* Vc = Vbuf[i & 1];

#pragma unroll
    for (int t = 0; t < 2; t++) {
      f32x16 st;
#pragma unroll
      for (int r = 0; r < 16; r++) st[r] = 0.f;
      __builtin_amdgcn_s_setprio(1);
      if (t == 0) {
#pragma unroll
        for (int s = 0; s < 4; s++)
          st = mfma32(*reinterpret_cast<const bf16x8*>(Kc + koff[s]), qf[s], st);
      } else {
#pragma unroll
        for (int s = 0; s < 4; s++)
          st = mfma32(*reinterpret_cast<const bf16x8*>(Kc + koff[s] + 2048), qf[s], st);
      }
      __builtin_amdgcn_s_setprio(0);

#pragma unroll
      for (int j = 0; j < 16; j += 4) {
        float p0 = EXP2(st[j + 0]);
        float p1 = EXP2(st[j + 1]);
        float p2 = EXP2(st[j + 2]);
        float p3 = EXP2(st[j + 3]);
        st[j + 0] = p0; st[j + 1] = p1; st[j + 2] = p2; st[j + 3] = p3;
        ps0 += p0 + p2; ps1 += p1 + p3;
      }

      u32 w0 = pk2(st[0], st[1]),   w1 = pk2(st[2], st[3]);
      u32 w2 = pk2(st[4], st[5]),   w3 = pk2(st[6], st[7]);
      u32 w4 = pk2(st[8], st[9]),   w5 = pk2(st[10], st[11]);
      u32 w6 = pk2(st[12], st[13]), w7 = pk2(st[14], st[15]);
      uint4 pa0, pa1;
#if __has_builtin(__builtin_amdgcn_permlane32_swap)
      auto r02 = __builtin_amdgcn_permlane32_swap(w0, w2, false, false);
      auto r13 = __builtin_amdgcn_permlane32_swap(w1, w3, false, false);
      auto r46 = __builtin_amdgcn_permlane32_swap(w4, w6, false, false);
      auto r57 = __builtin_amdgcn_permlane32_swap(w5, w7, false, false);
      pa0.x = (u32)r02[0]; pa0.y = (u32)r13[0]; pa0.z = (u32)r02[1]; pa0.w = (u32)r13[1];
      pa1.x = (u32)r46[0]; pa1.y = (u32)r57[0]; pa1.z = (u32)r46[1]; pa1.w = (u32)r57[1];
#else
      u32 ra2, rb2;
      ra2 = (u32)__shfl_xor((int)(h ? w0 : w2), 32);
      rb2 = (u32)__shfl_xor((int)(h ? w1 : w3), 32);
      pa0.x = h ? ra2 : w0; pa0.y = h ? rb2 : w1;
      pa0.z = h ? w0 : ra2; pa0.w = h ? w1 : rb2;
      ra2 = (u32)__shfl_xor((int)(h ? w4 : w6), 32);
      rb2 = (u32)__shfl_xor((int)(h ? w5 : w7), 32);
      pa1.x = h ? ra2 : w4; pa1.y = h ? rb2 : w5;
      pa1.z = h ? w4 : ra2; pa1.w = h ? w5 : rb2;
#endif
      union { uint4 u; bf16x8 v; } p0u, p1u;
      p0u.u = pa0; p1u.u = pa1;
      __builtin_amdgcn_s_setprio(1);
      if (t == 0) {
        oacc[0] = mfma32(p0u.v, *reinterpret_cast<const bf16x8*>(Vc + koff[0]), oacc[0]);
        oacc[0] = mfma32(p1u.v, *reinterpret_cast<const bf16x8*>(Vc + koff[1]), oacc[0]);
        oacc[1] = mfma32(p0u.v, *reinterpret_cast<const bf16x8*>(Vc + koff[0] + 2048), oacc[1]);
        oacc[1] = mfma32(p1u.v, *reinterpret_cast<const bf16x8*>(Vc + koff[1] + 2048), oacc[1]);
      } else {
        oacc[0] = mfma32(p0u.v, *reinterpret_cast<const bf16x8*>(Vc + koff[2]), oacc[0]);
        oacc[0] = mfma32(p1u.v, *reinterpret_cast<const bf16x8*>(Vc + koff[3]), oacc[0]);
        oacc[1] = mfma32(p0u.v, *reinterpret_cast<const bf16x8*>(Vc + koff[2] + 2048), oacc[1]);
        oacc[1] = mfma32(p1u.v, *reinterpret_cast<const bf16x8*>(Vc + koff[3] + 2048), oacc[1]);
      }
      __builtin_amdgcn_s_setprio(0);
    }
  }

  float lsum = ps0 + ps1;
  lsum += __shfl_xor(lsum, 32);

  u16* Op = Opart + (size_t)sp * 8192 * 512;
#pragma unroll
  for (int r = 0; r < 16; r++) {
    const int qr = (r & 3) + 8 * (r >> 2) + 4 * h;
    size_t row = (size_t)b * 2048 + qbase + qr;
#pragma unroll
    for (int dt = 0; dt < 2; dt++) {
      int col = hd * 64 + dt * 32 + lq;
      Op[row * 512 + col] = f2bf(oacc[dt][r]);
    }
  }
  if (h == 0)
    Stat[(size_t)sp * 32 * 2048 + (size_t)(b * 8 + hd) * 2048 + qbase + lq] = lsum;
}

extern "C" void kernel_launch(void* const* d_in, const int* in_sizes, int n_in,
                              void* d_out, int out_size, void* d_ws, size_t ws_size,
                              hipStream_t stream) {
  const float* x      = (const float*)d_in[0];
  const float* ln1_g  = (const float*)d_in[1];
  const float* ln1_b  = (const float*)d_in[2];
  const float* w_qkv  = (const float*)d_in[3];
  const float* b_qkv  = (const float*)d_in[4];
  const float* w_proj = (const float*)d_in[5];
  const float* b_proj = (const float*)d_in[6];
  const float* ln2_g  = (const float*)d_in[7];
  const float* ln2_b  = (const float*)d_in[8];
  const float* w1     = (const float*)d_in[9];
  const float* b1     = (const float*)d_in[10];
  const float* w2     = (const float*)d_in[11];
  const float* b2     = (const float*)d_in[12];
  float* out = (float*)d_out;

  const int M = 8192;  // B*N rows
  char* w = (char*)d_ws;
  u16* wqkvT  = (u16*)w; w += (size_t)1536 * 512 * 2;
  u16* wprojT = (u16*)w; w += (size_t)512 * 512 * 2;
  u16* w1T    = (u16*)w; w += (size_t)2048 * 512 * 2;
  u16* w2T    = (u16*)w; w += (size_t)512 * 2048 * 2;
  u16* h1     = (u16*)w; w += (size_t)M * 512 * 2;
  u16* Qb     = (u16*)w; w += (size_t)M * 512 * 2;
  u16* Kb     = (u16*)w; w += (size_t)M * 512 * 2;
  u16* VTb    = (u16*)w; w += (size_t)M * 512 * 2;
  u16* attn   = (u16*)w; w += (size_t)M * 512 * 2;   // (unused now)
  u16* h2     = (u16*)w; w += (size_t)M * 512 * 2;
  u16* mid    = (u16*)w; w += (size_t)M * 2048 * 2;   // reused as bf16 attn partials (2x8MB)
  float* Stat = (float*)w; w += (size_t)2 * 32 * 2048 * sizeof(float);
  u16* Opart = (u16*)mid;   // 16 MB, lifetime-disjoint with MLP mid

  prep_kernel<<<2816, 256, 0, stream>>>(w_qkv, wqkvT, w_proj, wprojT,
                                        w1, w1T, w2, w2T,
                                        x, ln1_g, ln1_b, h1);

  gemm_bt<0><<<dim3(1536 / 128, M / 128), 512, 0, stream>>>(
      h1, wqkvT, M, 1536, 512, b_qkv, nullptr, Qb, Kb, VTb);

  attn_kernel<<<dim3(32, 8, 4), 256, 0, stream>>>(Qb, Kb, VTb, Opart, Stat);

  proj_fused<<<dim3(512 / 64, M / 64), 256, 0, stream>>>(
      Opart, Stat, wprojT, b_proj, x, out);

  ln4_kernel<<<M / 4, 256, 0, stream>>>(out, ln2_g, ln2_b, h2);

  gemm_bt<2><<<dim3(2048 / 128, M / 128), 512, 0, stream>>>(
      h2, w1T, M, 2048, 512, b1, mid, nullptr, nullptr, nullptr);

  gemm_bt64<<<dim3(512 / 64, M / 64), 256, 0, stream>>>(
      mid, w2T, M, 512, 2048, b2, out, out);
}

// Round 21
// 161.329 us; speedup vs baseline: 1.0557x; 1.0557x over previous
//
#include <hip/hip_runtime.h>
#include <hip/hip_bf16.h>

typedef unsigned short u16;
typedef unsigned int u32;
typedef __attribute__((ext_vector_type(8))) __bf16 bf16x8;
typedef __attribute__((ext_vector_type(4))) float f32x4;
typedef __attribute__((ext_vector_type(16))) float f32x16;

#define LOG2E 1.4426950408889634f

__device__ __forceinline__ u16 f2bf(float f) {
  union { __hip_bfloat16 h; u16 u; } cv;
  cv.h = __float2bfloat16(f);
  return cv.u;
}

__device__ __forceinline__ float bf2f(u16 u) {
  union { u32 u; float f; } cv;
  cv.u = ((u32)u) << 16;
  return cv.f;
}

__device__ __forceinline__ u32 pk2(float a, float b) {
  return (u32)f2bf(a) | ((u32)f2bf(b) << 16);
}

// raw v_exp_f32 (2^x, ~1 ULP) — avoids OCML range-reduction sequence
#define EXP2 __builtin_amdgcn_exp2f

__device__ __forceinline__ f32x4 mfma16(bf16x8 a, bf16x8 b, f32x4 c) {
  return __builtin_amdgcn_mfma_f32_16x16x32_bf16(a, b, c, 0, 0, 0);
}
__device__ __forceinline__ f32x16 mfma32(bf16x8 a, bf16x8 b, f32x16 c) {
  return __builtin_amdgcn_mfma_f32_32x32x16_bf16(a, b, c, 0, 0, 0);
}

// async global->LDS, 16B per lane, dest = wave-uniform base + lane*16
__device__ __forceinline__ void gload16(const u16* g, u16* lds) {
  __builtin_amdgcn_global_load_lds(
      (const __attribute__((address_space(1))) u32*)g,
      (__attribute__((address_space(3))) u32*)lds, 16, 0, 0);
}

// ---- fused prep: 4x weight cast+transpose (LDS-tiled) + ln1 (one launch) ----
// blocks [0,768): casts; [768, 2816): ln1 rows (4 rows/block, 1 wave each).
__global__ __launch_bounds__(256) void prep_kernel(
    const float* __restrict__ w_qkv, u16* __restrict__ wqkvT,
    const float* __restrict__ w_proj, u16* __restrict__ wprojT,
    const float* __restrict__ w1, u16* __restrict__ w1T,
    const float* __restrict__ w2, u16* __restrict__ w2T,
    const float* __restrict__ X, const float* __restrict__ gam,
    const float* __restrict__ bet, u16* __restrict__ Y) {
  __shared__ float T[64][65];
  const int bid = blockIdx.x;
  if (bid < 768) {
    const float* W; u16* WT; int K, N, base;
    if (bid < 192)      { W = w_qkv; WT = wqkvT; K = 512;  N = 1536; base = 0; }
    else if (bid < 256) { W = w_proj; WT = wprojT; K = 512; N = 512; base = 192; }
    else if (bid < 512) { W = w1;   WT = w1T;   K = 512;  N = 2048; base = 256; }
    else                { W = w2;   WT = w2T;   K = 2048; N = 512;  base = 512; }
    int b = bid - base;
    int ntx = N >> 6;
    int bx = b % ntx, by = b / ntx;
    int tx = threadIdx.x & 63, ty = threadIdx.x >> 6;
#pragma unroll
    for (int i = 0; i < 64; i += 4)
      T[ty + i][tx] = W[(size_t)(by * 64 + ty + i) * N + bx * 64 + tx];
    __syncthreads();
#pragma unroll
    for (int i = 0; i < 64; i += 4)
      WT[(size_t)(bx * 64 + ty + i) * K + by * 64 + tx] = f2bf(T[tx][ty + i]);
  } else {
    int wid = threadIdx.x >> 6, l = threadIdx.x & 63;
    int row = (bid - 768) * 4 + wid;
    const float4* xp = reinterpret_cast<const float4*>(X + (size_t)row * 512);
    float4 a = xp[l], c = xp[l + 64];
    float s  = a.x + a.y + a.z + a.w + c.x + c.y + c.z + c.w;
    float s2 = a.x*a.x + a.y*a.y + a.z*a.z + a.w*a.w
             + c.x*c.x + c.y*c.y + c.z*c.z + c.w*c.w;
#pragma unroll
    for (int m = 1; m < 64; m <<= 1) { s += __shfl_xor(s, m); s2 += __shfl_xor(s2, m); }
    float mu = s * (1.f / 512.f);
    float rs = rsqrtf(s2 * (1.f / 512.f) - mu * mu + 1e-5f);
    const float4* gp = reinterpret_cast<const float4*>(gam);
    const float4* bp = reinterpret_cast<const float4*>(bet);
    float4 g0 = gp[l], g1 = gp[l + 64], b0 = bp[l], b1 = bp[l + 64];
    ushort4 o;
    o.x = f2bf((a.x - mu) * rs * g0.x + b0.x);
    o.y = f2bf((a.y - mu) * rs * g0.y + b0.y);
    o.z = f2bf((a.z - mu) * rs * g0.z + b0.z);
    o.w = f2bf((a.w - mu) * rs * g0.w + b0.w);
    reinterpret_cast<ushort4*>(Y + (size_t)row * 512)[l] = o;
    o.x = f2bf((c.x - mu) * rs * g1.x + b1.x);
    o.y = f2bf((c.y - mu) * rs * g1.y + b1.y);
    o.z = f2bf((c.z - mu) * rs * g1.z + b1.z);
    o.w = f2bf((c.w - mu) * rs * g1.w + b1.w);
    reinterpret_cast<ushort4*>(Y + (size_t)row * 512)[l + 64] = o;
  }
}

// ---- LayerNorm over 512, 4 waves/block (1 row per wave), f32 -> bf16 ----
__global__ __launch_bounds__(256) void ln4_kernel(const float* __restrict__ X,
                                                  const float* __restrict__ gam,
                                                  const float* __restrict__ bet,
                                                  u16* __restrict__ Y) {
  int wid = threadIdx.x >> 6, l = threadIdx.x & 63;
  int row = blockIdx.x * 4 + wid;
  const float4* xp = reinterpret_cast<const float4*>(X + (size_t)row * 512);
  float4 a = xp[l], c = xp[l + 64];
  float s  = a.x + a.y + a.z + a.w + c.x + c.y + c.z + c.w;
  float s2 = a.x*a.x + a.y*a.y + a.z*a.z + a.w*a.w
           + c.x*c.x + c.y*c.y + c.z*c.z + c.w*c.w;
#pragma unroll
  for (int m = 1; m < 64; m <<= 1) { s += __shfl_xor(s, m); s2 += __shfl_xor(s2, m); }
  float mu = s * (1.f / 512.f);
  float rs = rsqrtf(s2 * (1.f / 512.f) - mu * mu + 1e-5f);
  const float4* gp = reinterpret_cast<const float4*>(gam);
  const float4* bp = reinterpret_cast<const float4*>(bet);
  float4 g0 = gp[l], g1 = gp[l + 64], b0 = bp[l], b1 = bp[l + 64];
  ushort4 o;
  o.x = f2bf((a.x - mu) * rs * g0.x + b0.x);
  o.y = f2bf((a.y - mu) * rs * g0.y + b0.y);
  o.z = f2bf((a.z - mu) * rs * g0.z + b0.z);
  o.w = f2bf((a.w - mu) * rs * g0.w + b0.w);
  reinterpret_cast<ushort4*>(Y + (size_t)row * 512)[l] = o;
  o.x = f2bf((c.x - mu) * rs * g1.x + b1.x);
  o.y = f2bf((c.y - mu) * rs * g1.y + b1.y);
  o.z = f2bf((c.z - mu) * rs * g1.z + b1.z);
  o.w = f2bf((c.w - mu) * rs * g1.w + b1.w);
  reinterpret_cast<ushort4*>(Y + (size_t)row * 512)[l + 64] = o;
}

// ---- NT GEMM (BM=128, BK=64, 8 waves): qkv scatter & mlp1 gelu ----
// 8 granules/row, phys p = row*8 + (c ^ (row&7)); kk=1 read = off ^ 32 u16;
// +16-row fragment = +1024 u16 (imm-folded). 2-phase dbuf; XCD swizzle.
// EPI: 0=qkv scatter (V via ushort4)  2=gelu->bf16
template <int EPI>
__global__ __launch_bounds__(512)
__attribute__((amdgpu_waves_per_eu(4)))
void gemm_bt(const u16* __restrict__ A, const u16* __restrict__ BT,
             int M, int N, int K,
             const float* __restrict__ bias,
             u16* __restrict__ outU,
             u16* __restrict__ Qo, u16* __restrict__ Ko, u16* __restrict__ VTo) {
  constexpr int BM = 128, BN = 128, WC = 4, FM = 4;
  __shared__ u16 As[2][BM * 64];
  __shared__ u16 Bs[2][BN * 64];
  const int tid = threadIdx.x;
  const int wid = tid >> 6, l = tid & 63;
  const int lg = l >> 4, ll = l & 15;
  const int nx = gridDim.x;
  const int id = blockIdx.y * nx + blockIdx.x;
  const int cpx = (nx * gridDim.y) >> 3;
  const int wg = (id & 7) * cpx + (id >> 3);
  const int m0 = (wg / nx) * BM, n0 = (wg % nx) * BN;
  const int wm = (wid / WC) * (BM / 2), wn = (wid % WC) * 32;
  const f32x4 zf = {0.f, 0.f, 0.f, 0.f};
  f32x4 acc[FM][2];
#pragma unroll
  for (int i = 0; i < FM; i++) { acc[i][0] = zf; acc[i][1] = zf; }

  // staging: 1024 granules per matrix per buffer; 512 thr -> 2 each
  int srow[2], scol[2];
#pragma unroll
  for (int j = 0; j < 2; j++) {
    int p = j * 512 + tid;
    srow[j] = p >> 3;
    scol[j] = (p & 7) ^ (srow[j] & 7);
  }

  const int r0a = wm + ll;
  const int aoff0 = r0a * 64 + (lg ^ (r0a & 7)) * 8;
  const int r0b = wn + ll;
  const int boff0 = r0b * 64 + (lg ^ (r0b & 7)) * 8;

  auto stage = [&](int kt, int buf) {
#pragma unroll
    for (int j = 0; j < 2; j++) {
      int p = j * 512 + tid;
      gload16(A + (size_t)(m0 + srow[j]) * K + kt + scol[j] * 8, &As[buf][p * 8]);
      gload16(BT + (size_t)(n0 + srow[j]) * K + kt + scol[j] * 8, &Bs[buf][p * 8]);
    }
  };

  const int nt = K >> 6;
  stage(0, 0);
  for (int t = 0; t < nt; t++) {
    __syncthreads();
    if (t + 1 < nt) stage((t + 1) << 6, (t + 1) & 1);
    const u16* A_ = As[t & 1];
    const u16* B_ = Bs[t & 1];
#pragma unroll
    for (int kk = 0; kk < 2; kk++) {
      const int ax = kk ? (aoff0 ^ 32) : aoff0;
      const int bx = kk ? (boff0 ^ 32) : boff0;
      bf16x8 af[FM], bfr[2];
#pragma unroll
      for (int i = 0; i < FM; i++)
        af[i] = *reinterpret_cast<const bf16x8*>(A_ + ax + 1024 * i);
      bfr[0] = *reinterpret_cast<const bf16x8*>(B_ + bx);
      bfr[1] = *reinterpret_cast<const bf16x8*>(B_ + bx + 1024);
#pragma unroll
      for (int i = 0; i < FM; i++) {
        acc[i][0] = mfma16(af[i], bfr[0], acc[i][0]);
        acc[i][1] = mfma16(af[i], bfr[1], acc[i][1]);
      }
    }
  }

#pragma unroll
  for (int i = 0; i < FM; i++) {
#pragma unroll
    for (int j = 0; j < 2; j++) {
      int col = n0 + wn + j * 16 + ll;
      float bcol2 = bias[col];
      int rbase = m0 + wm + i * 16 + lg * 4;
      if (EPI == 0) {
        int bi = rbase >> 11, nseq0 = rbase & 2047;  // 4 rows stay in one b
        int t = col >> 9, rem = col & 511;
        int hh = rem >> 6, dd = rem & 63;
        if (t == 2) {
          // V transpose-scatter: 4 consecutive nseq -> one ushort4
          ushort4 v;
          v.x = f2bf(acc[i][j][0] + bcol2);
          v.y = f2bf(acc[i][j][1] + bcol2);
          v.z = f2bf(acc[i][j][2] + bcol2);
          v.w = f2bf(acc[i][j][3] + bcol2);
          *reinterpret_cast<ushort4*>(
              VTo + ((size_t)((bi << 3) + hh) * 64 + dd) * 2048 + nseq0) = v;
        } else {
          size_t hidx = ((size_t)((bi << 3) + hh) * 2048 + nseq0) * 64 + dd;
#pragma unroll
          for (int r = 0; r < 4; r++) {
            float val = acc[i][j][r] + bcol2;
            if (t == 0) Qo[hidx + (size_t)r * 64] = f2bf(val * (0.125f * LOG2E));
            else        Ko[hidx + (size_t)r * 64] = f2bf(val);
          }
        }
      } else {
#pragma unroll
        for (int r = 0; r < 4; r++) {
          float val = acc[i][j][r] + bcol2;
          // tanh-form GELU (|err| < 3e-3, overflow-safe via 1 - 2/(e+1))
          float y = 0.7978845608f * (val + 0.044715f * val * val * val);
          float e = EXP2(2.0f * LOG2E * y);
          float t2 = 1.0f - 2.0f / (e + 1.0f);
          outU[(size_t)(rbase + r) * 2048 + col] = f2bf(0.5f * val * (1.0f + t2));
        }
      }
    }
  }
}

// ---- NT GEMM (BM=BN=64, BK=64, 4 waves): proj & mlp2 (out = acc+bias+resid) ----
__global__ __launch_bounds__(256)
__attribute__((amdgpu_waves_per_eu(4)))
void gemm_bt64(const u16* __restrict__ A, const u16* __restrict__ BT,
               int M, int N, int K,
               const float* __restrict__ bias,
               const float* __restrict__ resid,
               float* __restrict__ outF) {
  __shared__ u16 As[2][64 * 64];
  __shared__ u16 Bs[2][64 * 64];
  const int tid = threadIdx.x;
  const int wid = tid >> 6, l = tid & 63;
  const int lg = l >> 4, ll = l & 15;
  const int nx = gridDim.x;
  const int id = blockIdx.y * nx + blockIdx.x;
  const int cpx = (nx * gridDim.y) >> 3;
  const int wg = (id & 7) * cpx + (id >> 3);
  const int m0 = (wg / nx) * 64, n0 = (wg % nx) * 64;
  const int wm = (wid >> 1) * 32, wn = (wid & 1) * 32;
  const f32x4 zf = {0.f, 0.f, 0.f, 0.f};
  f32x4 acc[2][2];
  acc[0][0] = zf; acc[0][1] = zf; acc[1][0] = zf; acc[1][1] = zf;

  int srow[2], scol[2];
#pragma unroll
  for (int j = 0; j < 2; j++) {
    int p = j * 256 + tid;
    srow[j] = p >> 3;
    scol[j] = (p & 7) ^ (srow[j] & 7);
  }

  const int ra = wm + ll;
  const int aoff0 = ra * 64 + (lg ^ (ra & 7)) * 8;
  const int rb = wn + ll;
  const int boff0 = rb * 64 + (lg ^ (rb & 7)) * 8;

  auto stage = [&](int kt, int buf) {
#pragma unroll
    for (int j = 0; j < 2; j++) {
      int p = j * 256 + tid;
      gload16(A + (size_t)(m0 + srow[j]) * K + kt + scol[j] * 8, &As[buf][p * 8]);
      gload16(BT + (size_t)(n0 + srow[j]) * K + kt + scol[j] * 8, &Bs[buf][p * 8]);
    }
  };

  const int nt = K >> 6;
  stage(0, 0);
  for (int t = 0; t < nt; t++) {
    __syncthreads();
    if (t + 1 < nt) stage((t + 1) << 6, (t + 1) & 1);
    const u16* A_ = As[t & 1];
    const u16* B_ = Bs[t & 1];
#pragma unroll
    for (int kk = 0; kk < 2; kk++) {
      const int ax = kk ? (aoff0 ^ 32) : aoff0;
      const int bx = kk ? (boff0 ^ 32) : boff0;
      bf16x8 a0 = *reinterpret_cast<const bf16x8*>(A_ + ax);
      bf16x8 a1 = *reinterpret_cast<const bf16x8*>(A_ + ax + 1024);
      bf16x8 b0 = *reinterpret_cast<const bf16x8*>(B_ + bx);
      bf16x8 b1 = *reinterpret_cast<const bf16x8*>(B_ + bx + 1024);
      acc[0][0] = mfma16(a0, b0, acc[0][0]);
      acc[0][1] = mfma16(a0, b1, acc[0][1]);
      acc[1][0] = mfma16(a1, b0, acc[1][0]);
      acc[1][1] = mfma16(a1, b1, acc[1][1]);
    }
  }

#pragma unroll
  for (int i = 0; i < 2; i++) {
#pragma unroll
    for (int j = 0; j < 2; j++) {
      int col = n0 + wn + j * 16 + ll;
      float bcol2 = bias[col];
      int rbase = m0 + wm + i * 16 + lg * 4;
#pragma unroll
      for (int r = 0; r < 4; r++) {
        size_t idx = (size_t)(rbase + r) * 512 + col;
        outF[idx] = acc[i][j][r] + bcol2 + resid[idx];
      }
    }
  }
}

// ---- flash attention: LDS-staged K/V, swapped-QK^T, fixed-base softmax,
// kvsplit=2 (1024 blocks = 4 blocks/CU = 4 waves/SIMD), sequential subtiles,
// koff folded, waves_per_eu(4).
// Q[B,H,N,D] (pre-scaled by 0.125*log2e), K[B,H,N,D], VT[B,H,D,N], all bf16.
// grid (32, 8, 4): x = qtile*2 + split; 4 waves; wave owns 32 q rows; KVBLK=64.
__global__ __launch_bounds__(256)
__attribute__((amdgpu_waves_per_eu(4)))
void attn_kernel(const u16* __restrict__ Q,
                 const u16* __restrict__ Kt,
                 const u16* __restrict__ VT,
                 u16* __restrict__ Opart,
                 float* __restrict__ Stat) {
  __shared__ __align__(16) u16 Kbuf[2][64 * 64];
  __shared__ __align__(16) u16 Vbuf[2][64 * 64];
  const int tid = threadIdx.x;
  const int wid = tid >> 6, l = tid & 63;
  const int lq = l & 31, h = l >> 5;
  const int b = blockIdx.z, hd = blockIdx.y;
  const int qt = blockIdx.x >> 1, sp = blockIdx.x & 1;
  const int qbase = qt * 128 + wid * 32;
  const int kv0 = sp * 1024;
  const size_t hoff = (size_t)(b * 8 + hd) * 2048 * 64;
  const u16* Qh = Q + hoff;
  const u16* Kh = Kt + hoff;
  const u16* Vh = VT + hoff;   // [D=64][N=2048]

  bf16x8 qf[4];
#pragma unroll
  for (int s = 0; s < 4; s++)
    qf[s] = *reinterpret_cast<const bf16x8*>(Qh + (size_t)(qbase + lq) * 64 + s * 16 + h * 8);

  int koff[4];
#pragma unroll
  for (int s = 0; s < 4; s++)
    koff[s] = (lq * 8 + ((s * 2 + h) ^ (lq & 7))) * 8;

  f32x16 oacc[2];
#pragma unroll
  for (int r = 0; r < 16; r++) { oacc[0][r] = 0.f; oacc[1][r] = 0.f; }
  float ps0 = 0.f, ps1 = 0.f;

  auto stage = [&](int kb, int buf) {
#pragma unroll
    for (int half = 0; half < 2; half++) {
      int g0 = half * 256 + wid * 64;        // wave-uniform base granule
      int p = g0 + l;
      int row = p >> 3;
      int c = (p & 7) ^ (row & 7);           // logical col16 stored at phys p
      gload16(Kh + (size_t)(kb + row) * 64 + c * 8, &Kbuf[buf][g0 * 8]);
      gload16(Vh + (size_t)row * 2048 + kb + c * 8, &Vbuf[buf][g0 * 8]);
    }
  };

  stage(kv0, 0);
  for (int i = 0; i < 16; i++) {
    __syncthreads();                          // drains vmcnt -> buf[i&1] ready
    if (i < 15) stage(kv0 + (i + 1) * 64, (i + 1) & 1);
    const u16* Kc = Kbuf[i & 1];
    const u16* Vc = Vbuf[i & 1];

#pragma unroll
    for (int t = 0; t < 2; t++) {
      f32x16 st;
#pragma unroll
      for (int r = 0; r < 16; r++) st[r] = 0.f;
      __builtin_amdgcn_s_setprio(1);
      if (t == 0) {
#pragma unroll
        for (int s = 0; s < 4; s++)
          st = mfma32(*reinterpret_cast<const bf16x8*>(Kc + koff[s]), qf[s], st);
      } else {
#pragma unroll
        for (int s = 0; s < 4; s++)
          st = mfma32(*reinterpret_cast<const bf16x8*>(Kc + koff[s] + 2048), qf[s], st);
      }
      __builtin_amdgcn_s_setprio(0);

#pragma unroll
      for (int j = 0; j < 16; j += 4) {
        float p0 = EXP2(st[j + 0]);
        float p1 = EXP2(st[j + 1]);
        float p2 = EXP2(st[j + 2]);
        float p3 = EXP2(st[j + 3]);
        st[j + 0] = p0; st[j + 1] = p1; st[j + 2] = p2; st[j + 3] = p3;
        ps0 += p0 + p2; ps1 += p1 + p3;
      }

      u32 w0 = pk2(st[0], st[1]),   w1 = pk2(st[2], st[3]);
      u32 w2 = pk2(st[4], st[5]),   w3 = pk2(st[6], st[7]);
      u32 w4 = pk2(st[8], st[9]),   w5 = pk2(st[10], st[11]);
      u32 w6 = pk2(st[12], st[13]), w7 = pk2(st[14], st[15]);
      uint4 pa0, pa1;
#if __has_builtin(__builtin_amdgcn_permlane32_swap)
      auto r02 = __builtin_amdgcn_permlane32_swap(w0, w2, false, false);
      auto r13 = __builtin_amdgcn_permlane32_swap(w1, w3, false, false);
      auto r46 = __builtin_amdgcn_permlane32_swap(w4, w6, false, false);
      auto r57 = __builtin_amdgcn_permlane32_swap(w5, w7, false, false);
      pa0.x = (u32)r02[0]; pa0.y = (u32)r13[0]; pa0.z = (u32)r02[1]; pa0.w = (u32)r13[1];
      pa1.x = (u32)r46[0]; pa1.y = (u32)r57[0]; pa1.z = (u32)r46[1]; pa1.w = (u32)r57[1];
#else
      u32 ra2, rb2;
      ra2 = (u32)__shfl_xor((int)(h ? w0 : w2), 32);
      rb2 = (u32)__shfl_xor((int)(h ? w1 : w3), 32);
      pa0.x = h ? ra2 : w0; pa0.y = h ? rb2 : w1;
      pa0.z = h ? w0 : ra2; pa0.w = h ? w1 : rb2;
      ra2 = (u32)__shfl_xor((int)(h ? w4 : w6), 32);
      rb2 = (u32)__shfl_xor((int)(h ? w5 : w7), 32);
      pa1.x = h ? ra2 : w4; pa1.y = h ? rb2 : w5;
      pa1.z = h ? w4 : ra2; pa1.w = h ? w5 : rb2;
#endif
      union { uint4 u; bf16x8 v; } p0u, p1u;
      p0u.u = pa0; p1u.u = pa1;
      __builtin_amdgcn_s_setprio(1);
      if (t == 0) {
        oacc[0] = mfma32(p0u.v, *reinterpret_cast<const bf16x8*>(Vc + koff[0]), oacc[0]);
        oacc[0] = mfma32(p1u.v, *reinterpret_cast<const bf16x8*>(Vc + koff[1]), oacc[0]);
        oacc[1] = mfma32(p0u.v, *reinterpret_cast<const bf16x8*>(Vc + koff[0] + 2048), oacc[1]);
        oacc[1] = mfma32(p1u.v, *reinterpret_cast<const bf16x8*>(Vc + koff[1] + 2048), oacc[1]);
      } else {
        oacc[0] = mfma32(p0u.v, *reinterpret_cast<const bf16x8*>(Vc + koff[2]), oacc[0]);
        oacc[0] = mfma32(p1u.v, *reinterpret_cast<const bf16x8*>(Vc + koff[3]), oacc[0]);
        oacc[1] = mfma32(p0u.v, *reinterpret_cast<const bf16x8*>(Vc + koff[2] + 2048), oacc[1]);
        oacc[1] = mfma32(p1u.v, *reinterpret_cast<const bf16x8*>(Vc + koff[3] + 2048), oacc[1]);
      }
      __builtin_amdgcn_s_setprio(0);
    }
  }

  float lsum = ps0 + ps1;
  lsum += __shfl_xor(lsum, 32);

  u16* Op = Opart + (size_t)sp * 8192 * 512;
#pragma unroll
  for (int r = 0; r < 16; r++) {
    const int qr = (r & 3) + 8 * (r >> 2) + 4 * h;
    size_t row = (size_t)b * 2048 + qbase + qr;
#pragma unroll
    for (int dt = 0; dt < 2; dt++) {
      int col = hd * 64 + dt * 32 + lq;
      Op[row * 512 + col] = f2bf(oacc[dt][r]);
    }
  }
  if (h == 0)
    Stat[(size_t)sp * 32 * 2048 + (size_t)(b * 8 + hd) * 2048 + qbase + lq] = lsum;
}

// combine the two KV-split partials: O = sum_p O_p / sum_p l_p
__global__ __launch_bounds__(256) void attn_merge(const u16* __restrict__ Opart,
                                                  const float* __restrict__ Stat,
                                                  u16* __restrict__ O) {
  int gid = blockIdx.x * 256 + threadIdx.x;   // 8192 rows * 64 chunks
  int row = gid >> 6;
  int c8 = (gid & 63) * 8;
  int hd = c8 >> 6;
  int bh = (row >> 11) * 8 + hd;
  int n = row & 2047;
  float L = Stat[(size_t)bh * 2048 + n] +
            Stat[(size_t)32 * 2048 + (size_t)bh * 2048 + n];
  float acc[8];
#pragma unroll
  for (int j = 0; j < 8; j++) acc[j] = 0.f;
#pragma unroll
  for (int p = 0; p < 2; p++) {
    const ushort4* pp = reinterpret_cast<const ushort4*>(
        Opart + (size_t)p * 8192 * 512 + (size_t)row * 512 + c8);
    ushort4 v0 = pp[0], v1 = pp[1];
    acc[0] += bf2f(v0.x); acc[1] += bf2f(v0.y);
    acc[2] += bf2f(v0.z); acc[3] += bf2f(v0.w);
    acc[4] += bf2f(v1.x); acc[5] += bf2f(v1.y);
    acc[6] += bf2f(v1.z); acc[7] += bf2f(v1.w);
  }
  float li = 1.0f / L;
  ushort4 o0, o1;
  o0.x = f2bf(acc[0] * li); o0.y = f2bf(acc[1] * li);
  o0.z = f2bf(acc[2] * li); o0.w = f2bf(acc[3] * li);
  o1.x = f2bf(acc[4] * li); o1.y = f2bf(acc[5] * li);
  o1.z = f2bf(acc[6] * li); o1.w = f2bf(acc[7] * li);
  ushort4* op = reinterpret_cast<ushort4*>(O + (size_t)row * 512 + c8);
  op[0] = o0;
  op[1] = o1;
}

extern "C" void kernel_launch(void* const* d_in, const int* in_sizes, int n_in,
                              void* d_out, int out_size, void* d_ws, size_t ws_size,
                              hipStream_t stream) {
  const float* x      = (const float*)d_in[0];
  const float* ln1_g  = (const float*)d_in[1];
  const float* ln1_b  = (const float*)d_in[2];
  const float* w_qkv  = (const float*)d_in[3];
  const float* b_qkv  = (const float*)d_in[4];
  const float* w_proj = (const float*)d_in[5];
  const float* b_proj = (const float*)d_in[6];
  const float* ln2_g  = (const float*)d_in[7];
  const float* ln2_b  = (const float*)d_in[8];
  const float* w1     = (const float*)d_in[9];
  const float* b1     = (const float*)d_in[10];
  const float* w2     = (const float*)d_in[11];
  const float* b2     = (const float*)d_in[12];
  float* out = (float*)d_out;

  const int M = 8192;  // B*N rows
  char* w = (char*)d_ws;
  u16* wqkvT  = (u16*)w; w += (size_t)1536 * 512 * 2;
  u16* wprojT = (u16*)w; w += (size_t)512 * 512 * 2;
  u16* w1T    = (u16*)w; w += (size_t)2048 * 512 * 2;
  u16* w2T    = (u16*)w; w += (size_t)512 * 2048 * 2;
  u16* h1     = (u16*)w; w += (size_t)M * 512 * 2;
  u16* Qb     = (u16*)w; w += (size_t)M * 512 * 2;
  u16* Kb     = (u16*)w; w += (size_t)M * 512 * 2;
  u16* VTb    = (u16*)w; w += (size_t)M * 512 * 2;
  u16* attn   = (u16*)w; w += (size_t)M * 512 * 2;
  u16* h2     = (u16*)w; w += (size_t)M * 512 * 2;
  u16* mid    = (u16*)w; w += (size_t)M * 2048 * 2;   // reused as bf16 attn partials (2x8MB)
  float* Stat = (float*)w; w += (size_t)2 * 32 * 2048 * sizeof(float);
  u16* Opart = (u16*)mid;   // 16 MB, lifetime-disjoint with MLP mid

  prep_kernel<<<2816, 256, 0, stream>>>(w_qkv, wqkvT, w_proj, wprojT,
                                        w1, w1T, w2, w2T,
                                        x, ln1_g, ln1_b, h1);

  gemm_bt<0><<<dim3(1536 / 128, M / 128), 512, 0, stream>>>(
      h1, wqkvT, M, 1536, 512, b_qkv, nullptr, Qb, Kb, VTb);

  attn_kernel<<<dim3(32, 8, 4), 256, 0, stream>>>(Qb, Kb, VTb, Opart, Stat);
  attn_merge<<<M * 64 / 256, 256, 0, stream>>>(Opart, Stat, attn);

  gemm_bt64<<<dim3(512 / 64, M / 64), 256, 0, stream>>>(
      attn, wprojT, M, 512, 512, b_proj, x, out);

  ln4_kernel<<<M / 4, 256, 0, stream>>>(out, ln2_g, ln2_b, h2);

  gemm_bt<2><<<dim3(2048 / 128, M / 128), 512, 0, stream>>>(
      h2, w1T, M, 2048, 512, b1, mid, nullptr, nullptr, nullptr);

  gemm_bt64<<<dim3(512 / 64, M / 64), 256, 0, stream>>>(
      mid, w2T, M, 512, 2048, b2, out, out);
}